// Round 1
// baseline (461.154 us; speedup 1.0000x reference)
//
#include <hip/hip_runtime.h>
#include <math.h>

// NoisyTopkRouter: B=8,T=4096,NE=1024,E=16,TOPK=2,LIN=1824
// tokens = 32768; streamed features = 1792 (city-32 folded into a constant)
// out = [router 32768*16][indices 32768*2][gate1 32768*16] all f32
//
// R5: occupancy fix. Same data flow as R4 (128 tok/block, 64-k chunks,
// A dbuf [2][128][68] + W dbuf [2][64][36], lane tile 8 tok x 8 e, LDS-instr
// ratio 1/16) but 1024 threads -> 16 waves/CU (was 8 = 2/SIMD, latency-bound:
// VALUBusy 27%, Occ 20%, HBM 13%, floors ~36us vs measured 115us).
// 16-way split-K (k-slab 4/wave/chunk); waves 0-7 reduce into sS0, 8-15 into
// sS1 concurrently (still 8 serial-RMW rounds); epilogue sums both.
// VGPR <=128 required for 16 waves/CU: hold 8 W-frags (32 reg) + single a.

#define TOKS 128
#define NCHUNK 28
#define I_OFF 524288        // 32768*16
#define G_OFF 589824        // 524288 + 32768*2
#define SA 68               // pad 64->68: bank stride 4 -> 2-way (free, m136)
#define SW 36               // pad 32->36: conflict-free
#define SS 36               // score rows

__device__ __forceinline__ float softplus_f(float x) {
  // jax.nn.softplus = max(x,0) + log1p(exp(-|x|))
  return fmaxf(x, 0.0f) + log1pf(expf(-fabsf(x)));
}

#define FMA8(s, wa, wb, j)                         \
  accL[j].x = fmaf(s, wa.x, accL[j].x);            \
  accL[j].y = fmaf(s, wa.y, accL[j].y);            \
  accL[j].z = fmaf(s, wa.z, accL[j].z);            \
  accL[j].w = fmaf(s, wa.w, accL[j].w);            \
  accH[j].x = fmaf(s, wb.x, accH[j].x);            \
  accH[j].y = fmaf(s, wb.y, accH[j].y);            \
  accH[j].z = fmaf(s, wb.z, accH[j].z);            \
  accH[j].w = fmaf(s, wb.w, accH[j].w);

__global__ __launch_bounds__(1024, 4) void router_kernel(
    const float* __restrict__ mh, const float* __restrict__ dt,
    const float* __restrict__ dd, const float* __restrict__ rg,
    const float* __restrict__ de, const float* __restrict__ cemb_all,
    const float* __restrict__ w_route, const float* __restrict__ b_route,
    const float* __restrict__ w_noise, const float* __restrict__ b_noise,
    const float* __restrict__ eps, const int* __restrict__ city_index,
    float* __restrict__ out) {
  // A dbuf 2*128*68=17408 f | W dbuf 2*64*36=4608 f ; scores overlay after end
  __shared__ float smem[22016];
  __shared__ float city_l[32];
  float* sA0 = smem;
  float* sA1 = smem + 8704;
  float* sW0 = smem + 17408;
  float* sW1 = smem + 19712;
  float* sS0 = smem;          // after final barrier: waves 0-7 partials
  float* sS1 = smem + 4608;   // waves 8-15 partials

  const int tid = threadIdx.x;
  const int w   = tid >> 6;        // wave 0..15: k-slab [w*4, w*4+4) per chunk
  const int ln  = tid & 63;
  const int tg  = ln & 15;         // tokens {tg + 16j}, j=0..7
  const int eg  = ln >> 4;         // e-cols eg*8..eg*8+7 (of 32 = route|noise)
  const int blockTok = blockIdx.x * TOKS;

  // ---- constant: bias + city_embed . W[1024:1056] ----
  if (tid < 32) {
    const int e = tid & 15;
    const float* wsrc = (tid < 16) ? w_route : w_noise;
    const float* bsrc = (tid < 16) ? b_route : b_noise;
    const float* ce = cemb_all + city_index[0] * 32;
    float s = bsrc[e];
#pragma unroll
    for (int j = 0; j < 32; ++j) s = fmaf(ce[j], wsrc[(1024 + j) * 16 + e], s);
    city_l[tid] = s;
  }

  float4 accL[8], accH[8];
#pragma unroll
  for (int j = 0; j < 8; ++j) {
    accL[j] = make_float4(0.f, 0.f, 0.f, 0.f);
    accH[j] = make_float4(0.f, 0.f, 0.f, 0.f);
  }

  // staging coords: A tile 128 rows x 16 float4 (2048 f4 / 1024 thr = 2 each),
  // W chunk 64 rows x 8 float4 (512 f4: tid<512, 1 each). All coalesced.
  const int arow = tid >> 4;           // 0..63; rows arow and arow+64
  const int acol = (tid & 15) * 4;
  const int wrow = tid >> 3;           // 0..63 (tid<512)
  const int wcol = tid & 7;

  float4 AR0, AR1, WR;  // named regs: no scratch

  auto a_src = [&](int g, int row) -> const float* {
    const float* base; int stride;
    if (g < 16)      { base = mh + g * 64;        stride = 1024; }
    else if (g < 20) { base = dt + (g - 16) * 64; stride = 256; }
    else if (g < 24) { base = dd + (g - 20) * 64; stride = 256; }
    else if (g < 26) { base = rg + (g - 24) * 64; stride = 128; }
    else             { base = de + (g - 26) * 64; stride = 128; }
    return base + (size_t)(blockTok + row) * stride;
  };

  auto prefetch = [&](int g) {
    AR0 = *(const float4*)(a_src(g, arow +  0) + acol);
    AR1 = *(const float4*)(a_src(g, arow + 64) + acol);
    if (tid < 512) {
      const int kb = g * 64 + ((g >= 16) ? 32 : 0);  // skip city rows
      const float* ws = (wcol < 4)
          ? (w_route + (kb + wrow) * 16 + wcol * 4)
          : (w_noise + (kb + wrow) * 16 + (wcol - 4) * 4);
      WR = *(const float4*)ws;
    }
  };

  auto stage = [&](float* A, float* W) {
    *(float4*)&A[(arow +  0) * SA + acol] = AR0;
    *(float4*)&A[(arow + 64) * SA + acol] = AR1;
    if (tid < 512) *(float4*)&W[wrow * SW + wcol * 4] = WR;
  };

  prefetch(0);
  stage(sA0, sW0);
  __syncthreads();

  const int k0 = w * 4;  // this wave's 4-k slab within each 64-k chunk

  for (int c = 0; c < NCHUNK; ++c) {
    const float* A = (c & 1) ? sA1 : sA0;
    const float* W = (c & 1) ? sW1 : sW0;

    if (c + 1 < NCHUNK) prefetch(c + 1);  // global loads fly over compute

    // 8 W-fragments for this wave's 4 k-rows (broadcast reads, 32 VGPR)
    float4 wA0 = *(const float4*)&W[(k0 + 0) * SW + eg * 8];
    float4 wB0 = *(const float4*)&W[(k0 + 0) * SW + eg * 8 + 4];
    float4 wA1 = *(const float4*)&W[(k0 + 1) * SW + eg * 8];
    float4 wB1 = *(const float4*)&W[(k0 + 1) * SW + eg * 8 + 4];
    float4 wA2 = *(const float4*)&W[(k0 + 2) * SW + eg * 8];
    float4 wB2 = *(const float4*)&W[(k0 + 2) * SW + eg * 8 + 4];
    float4 wA3 = *(const float4*)&W[(k0 + 3) * SW + eg * 8];
    float4 wB3 = *(const float4*)&W[(k0 + 3) * SW + eg * 8 + 4];

#pragma unroll
    for (int j = 0; j < 8; ++j) {
      float4 a = *(const float4*)&A[(tg + 16 * j) * SA + k0];  // 2-way: free
      FMA8(a.x, wA0, wB0, j);
      FMA8(a.y, wA1, wB1, j);
      FMA8(a.z, wA2, wB2, j);
      FMA8(a.w, wA3, wB3, j);
    }

    if (c + 1 < NCHUNK) stage((c & 1) ? sA0 : sA1, (c & 1) ? sW0 : sW1);
    __syncthreads();  // next buffer visible; all waves done with current
  }

  // ---- split-K reduction: 8 serial-RMW rounds, two buffers in parallel ----
  // waves 0-7 (k 0..31) -> sS0 ; waves 8-15 (k 32..63) -> sS1
  // (all of smem is dead here: compute loop fully barriered above)
  for (int r = 0; r < 8; ++r) {
    if ((w & 7) == r) {
      float* S = (w < 8) ? sS0 : sS1;
#pragma unroll
      for (int j = 0; j < 8; ++j) {
        float* p = &S[(tg + 16 * j) * SS + eg * 8];
        if (r == 0) {
          *(float4*)(p)     = accL[j];
          *(float4*)(p + 4) = accH[j];
        } else {
          float4 x0 = *(float4*)(p), x1 = *(float4*)(p + 4);
          x0.x += accL[j].x; x0.y += accL[j].y; x0.z += accL[j].z; x0.w += accL[j].w;
          x1.x += accH[j].x; x1.y += accH[j].y; x1.z += accH[j].z; x1.w += accH[j].w;
          *(float4*)(p)     = x0;
          *(float4*)(p + 4) = x1;
        }
      }
    }
    __syncthreads();
  }

  // ---- epilogue: one lane per token ----
  if (tid < TOKS) {
    const int tokg = blockTok + tid;
    float l[32];
#pragma unroll
    for (int e4 = 0; e4 < 8; ++e4) {
      float4 s0 = *(const float4*)&sS0[tid * SS + e4 * 4];
      float4 s1 = *(const float4*)&sS1[tid * SS + e4 * 4];
      l[e4 * 4 + 0] = s0.x + s1.x;
      l[e4 * 4 + 1] = s0.y + s1.y;
      l[e4 * 4 + 2] = s0.z + s1.z;
      l[e4 * 4 + 3] = s0.w + s1.w;
    }
#pragma unroll
    for (int e = 0; e < 32; ++e) l[e] += city_l[e];

    const float* ep = eps + (size_t)tokg * 16;
    float n[16];
#pragma unroll
    for (int e = 0; e < 16; ++e)
      n[e] = fmaf(ep[e], softplus_f(l[16 + e]), l[e]);

    // top-2, lowest-index tie-break (matches lax.top_k)
    float m1 = -INFINITY; int i1 = 0;
#pragma unroll
    for (int e = 0; e < 16; ++e)
      if (n[e] > m1) { m1 = n[e]; i1 = e; }
    float m2 = -INFINITY; int i2 = 0;
#pragma unroll
    for (int e = 0; e < 16; ++e)
      if (e != i1 && n[e] > m2) { m2 = n[e]; i2 = e; }

    float ex[16], Z = 0.f;
#pragma unroll
    for (int e = 0; e < 16; ++e) { ex[e] = expf(n[e] - m1); Z += ex[e]; }
    const float invZ  = 1.0f / Z;
    const float invZ2 = 1.0f / (1.0f + expf(m2 - m1));  // ex[i1]=1

    float r[16], g1[16];
#pragma unroll
    for (int e = 0; e < 16; ++e) {
      r[e]  = (e == i1 || e == i2) ? ex[e] * invZ2 : 0.0f;
      g1[e] = ex[e] * invZ;
    }

    float* ro = out + (size_t)tokg * 16;
#pragma unroll
    for (int e4 = 0; e4 < 4; ++e4)
      *(float4*)(ro + e4 * 4) = make_float4(r[e4*4], r[e4*4+1], r[e4*4+2], r[e4*4+3]);

    out[I_OFF + (size_t)tokg * 2 + 0] = (float)i1;
    out[I_OFF + (size_t)tokg * 2 + 1] = (float)i2;

    float* go = out + G_OFF + (size_t)tokg * 16;
#pragma unroll
    for (int e4 = 0; e4 < 4; ++e4)
      *(float4*)(go + e4 * 4) = make_float4(g1[e4*4], g1[e4*4+1], g1[e4*4+2], g1[e4*4+3]);
  }
}

extern "C" void kernel_launch(void* const* d_in, const int* in_sizes, int n_in,
                              void* d_out, int out_size, void* d_ws, size_t ws_size,
                              hipStream_t stream) {
  const float* mh = (const float*)d_in[0];   // [8,4096,1024]
  const float* dt = (const float*)d_in[1];   // [8,4096,256]
  const float* dd = (const float*)d_in[2];   // [8,4096,256]
  const float* rg = (const float*)d_in[3];   // [8,4096,128]
  const float* de = (const float*)d_in[4];   // [8,4096,128]
  const float* ce = (const float*)d_in[5];   // [4,32]
  const float* wr = (const float*)d_in[6];   // [1824,16]
  const float* br = (const float*)d_in[7];   // [16]
  const float* wn = (const float*)d_in[8];   // [1824,16]
  const float* bn = (const float*)d_in[9];   // [16]
  const float* ep = (const float*)d_in[10];  // [8,4096,16]
  const int*   ci = (const int*)d_in[11];    // scalar
  float* out = (float*)d_out;

  router_kernel<<<256, 1024, 0, stream>>>(mh, dt, dd, rg, de, ce, wr, br, wn, bn,
                                          ep, ci, out);
}

// Round 2
// 333.562 us; speedup vs baseline: 1.3825x; 1.3825x over previous
//
#include <hip/hip_runtime.h>
#include <math.h>

// NoisyTopkRouter: B=8,T=4096,NE=1024,E=16,TOPK=2,LIN=1824
// tokens = 32768; streamed features = 1792 (city-32 folded into a constant)
// out = [router 32768*16][indices 32768*2][gate1 32768*16] all f32
//
// R6: kill the LDS-issue floor (R4: ~296 b128/chunk/CU = 41us > 24us VALU
// floor; half of those were W-fragment broadcasts). W rows are wave-uniform
// -> scalar loads (s_load via readfirstlane-uniform pointers), never touch
// LDS/VGPR frags. Lane = 1 token x all 32 e (acc 32 VGPR); 8 waves split K
// (8-k slab). Per chunk per lane: 2 ds_read_b128 + 2 ds_write_b128 + 256
// v_fmac. TOKS=64 -> grid 512 -> 2 blocks/CU (LDS 34KB), 16 waves/CU.
// R5 lesson: launch_bounds 2nd arg acts CUDA-style (min blocks/CU);
// (1024,4) forced VGPR=64 -> 423MB spill traffic. (512,2) -> cap 128.

#define TOKS 64
#define NCHUNK 28
#define I_OFF 524288        // 32768*16
#define G_OFF 589824        // 524288 + 32768*2
#define SA 65               // row stride: bank=(ln+k)%32 -> 2-way (free, m136)
#define SP 33               // reduction slab row stride: 2-way, free

__device__ __forceinline__ float softplus_f(float x) {
  // jax.nn.softplus = max(x,0) + log1p(exp(-|x|))
  return fmaxf(x, 0.0f) + log1pf(expf(-fabsf(x)));
}

__global__ __launch_bounds__(512, 2) void router_kernel(
    const float* __restrict__ mh, const float* __restrict__ dt,
    const float* __restrict__ dd, const float* __restrict__ rg,
    const float* __restrict__ de, const float* __restrict__ cemb_all,
    const float* __restrict__ w_route, const float* __restrict__ b_route,
    const float* __restrict__ w_noise, const float* __restrict__ b_noise,
    const float* __restrict__ eps, const int* __restrict__ city_index,
    float* __restrict__ out) {
  // A dbuf 2*64*65 = 8320 f; reduction overlay 4*64*33 = 8448 f (max)
  __shared__ float smem[8448];
  __shared__ float city_l[32];
  float* sA0 = smem;
  float* sA1 = smem + 4160;

  const int tid = threadIdx.x;
  const int ln  = tid & 63;                              // lane = token
  const int w   = tid >> 6;                              // wave 0..7
  const int wu  = __builtin_amdgcn_readfirstlane(w);     // uniform wave id
  const int k0  = wu * 8;                                // k-slab in chunk
  const int blockTok = blockIdx.x * TOKS;

  // ---- constant: bias + city_embed . W[1024:1056] ----
  if (tid < 32) {
    const int e = tid & 15;
    const float* wsrc = (tid < 16) ? w_route : w_noise;
    const float* bsrc = (tid < 16) ? b_route : b_noise;
    const float* ce = cemb_all + city_index[0] * 32;
    float s = bsrc[e];
#pragma unroll
    for (int j = 0; j < 32; ++j) s = fmaf(ce[j], wsrc[(1024 + j) * 16 + e], s);
    city_l[tid] = s;
  }

  float accR[16], accN[16];
#pragma unroll
  for (int e = 0; e < 16; ++e) { accR[e] = 0.f; accN[e] = 0.f; }

  // A staging: chunk = 64 tok x 64 k = 1024 f4 / 512 thr = 2 f4 each.
  const int arow = tid >> 4;           // 0..31; rows arow and arow+32
  const int acol = (tid & 15) * 4;

  float4 AR0, AR1;  // named regs: no scratch

  auto a_src = [&](int g, int row) -> const float* {
    const float* base; int stride;
    if (g < 16)      { base = mh + g * 64;        stride = 1024; }
    else if (g < 20) { base = dt + (g - 16) * 64; stride = 256; }
    else if (g < 24) { base = dd + (g - 20) * 64; stride = 256; }
    else             { base = (g < 26) ? rg + (g - 24) * 64
                                       : de + (g - 26) * 64;
                       stride = 128; }
    return base + (size_t)(blockTok + row) * stride;
  };

  auto prefetch = [&](int g) {
    AR0 = *(const float4*)(a_src(g, arow +  0) + acol);
    AR1 = *(const float4*)(a_src(g, arow + 32) + acol);
  };

  auto stage = [&](float* A) {
    *(float4*)&A[(arow +  0) * SA + acol] = AR0;
    *(float4*)&A[(arow + 32) * SA + acol] = AR1;
  };

  prefetch(0);
  stage(sA0);
  __syncthreads();

  for (int c = 0; c < NCHUNK; ++c) {
    const float* A = (c & 1) ? sA1 : sA0;

    if (c + 1 < NCHUNK) prefetch(c + 1);  // global loads fly over compute

    // wave-uniform W row base (skips city rows 1024..1055 of the 1824)
    const int kb = c * 64 + ((c >= 16) ? 32 : 0) + k0;
    const float* wr = w_route + (size_t)kb * 16;   // uniform -> s_load
    const float* wn = w_noise + (size_t)kb * 16;   // uniform -> s_load

    // this lane's token, this wave's 8-k slab
    float4 a0 = *(const float4*)&A[ln * SA + k0];
    float4 a1 = *(const float4*)&A[ln * SA + k0 + 4];

#pragma unroll
    for (int r = 0; r < 8; ++r) {
      const float ak = (r == 0) ? a0.x : (r == 1) ? a0.y : (r == 2) ? a0.z
                     : (r == 3) ? a0.w : (r == 4) ? a1.x : (r == 5) ? a1.y
                     : (r == 6) ? a1.z : a1.w;
#pragma unroll
      for (int e = 0; e < 16; ++e) {
        accR[e] = fmaf(wr[r * 16 + e], ak, accR[e]);  // v_fmac v,s,v
        accN[e] = fmaf(wn[r * 16 + e], ak, accN[e]);
      }
    }

    if (c + 1 < NCHUNK) stage((c & 1) ? sA0 : sA1);
    __syncthreads();  // next buffer visible; all waves done with current
  }

  // ---- split-K tree reduction: 8 partials -> wave 0 registers ----
  // slabs sP[slot][64][33] overlay the (dead) A double-buffer.
  auto writeP = [&](int slot) {
    float* p = &smem[slot * 2112 + ln * SP];
    *(float4*)(p +  0) = make_float4(accR[0],  accR[1],  accR[2],  accR[3]);
    *(float4*)(p +  4) = make_float4(accR[4],  accR[5],  accR[6],  accR[7]);
    *(float4*)(p +  8) = make_float4(accR[8],  accR[9],  accR[10], accR[11]);
    *(float4*)(p + 12) = make_float4(accR[12], accR[13], accR[14], accR[15]);
    *(float4*)(p + 16) = make_float4(accN[0],  accN[1],  accN[2],  accN[3]);
    *(float4*)(p + 20) = make_float4(accN[4],  accN[5],  accN[6],  accN[7]);
    *(float4*)(p + 24) = make_float4(accN[8],  accN[9],  accN[10], accN[11]);
    *(float4*)(p + 28) = make_float4(accN[12], accN[13], accN[14], accN[15]);
  };
  auto addP = [&](int slot) {
    const float* p = &smem[slot * 2112 + ln * SP];
    float4 x;
    x = *(const float4*)(p +  0); accR[0] += x.x; accR[1] += x.y; accR[2] += x.z; accR[3] += x.w;
    x = *(const float4*)(p +  4); accR[4] += x.x; accR[5] += x.y; accR[6] += x.z; accR[7] += x.w;
    x = *(const float4*)(p +  8); accR[8] += x.x; accR[9] += x.y; accR[10] += x.z; accR[11] += x.w;
    x = *(const float4*)(p + 12); accR[12] += x.x; accR[13] += x.y; accR[14] += x.z; accR[15] += x.w;
    x = *(const float4*)(p + 16); accN[0] += x.x; accN[1] += x.y; accN[2] += x.z; accN[3] += x.w;
    x = *(const float4*)(p + 20); accN[4] += x.x; accN[5] += x.y; accN[6] += x.z; accN[7] += x.w;
    x = *(const float4*)(p + 24); accN[8] += x.x; accN[9] += x.y; accN[10] += x.z; accN[11] += x.w;
    x = *(const float4*)(p + 28); accN[12] += x.x; accN[13] += x.y; accN[14] += x.z; accN[15] += x.w;
  };

  if (w >= 4) writeP(w - 4);        // waves 4..7 -> slots 0..3
  __syncthreads();
  if (w < 4) addP(w);
  __syncthreads();
  if (w == 2 || w == 3) writeP(w - 2);
  __syncthreads();
  if (w < 2) addP(w);
  __syncthreads();
  if (w == 1) writeP(0);
  __syncthreads();

  // ---- epilogue: wave 0, one lane per token, logits in registers ----
  if (w == 0) {
    addP(0);
    const int tokg = blockTok + ln;
    float l[32];
#pragma unroll
    for (int e = 0; e < 16; ++e) {
      l[e]      = accR[e] + city_l[e];
      l[16 + e] = accN[e] + city_l[16 + e];
    }

    const float* ep = eps + (size_t)tokg * 16;
    float n[16];
#pragma unroll
    for (int e = 0; e < 16; ++e)
      n[e] = fmaf(ep[e], softplus_f(l[16 + e]), l[e]);

    // top-2, lowest-index tie-break (matches lax.top_k)
    float m1 = -INFINITY; int i1 = 0;
#pragma unroll
    for (int e = 0; e < 16; ++e)
      if (n[e] > m1) { m1 = n[e]; i1 = e; }
    float m2 = -INFINITY; int i2 = 0;
#pragma unroll
    for (int e = 0; e < 16; ++e)
      if (e != i1 && n[e] > m2) { m2 = n[e]; i2 = e; }

    float ex[16], Z = 0.f;
#pragma unroll
    for (int e = 0; e < 16; ++e) { ex[e] = expf(n[e] - m1); Z += ex[e]; }
    const float invZ  = 1.0f / Z;
    const float invZ2 = 1.0f / (1.0f + expf(m2 - m1));  // ex[i1]=1

    float r[16], g1[16];
#pragma unroll
    for (int e = 0; e < 16; ++e) {
      r[e]  = (e == i1 || e == i2) ? ex[e] * invZ2 : 0.0f;
      g1[e] = ex[e] * invZ;
    }

    float* ro = out + (size_t)tokg * 16;
#pragma unroll
    for (int e4 = 0; e4 < 4; ++e4)
      *(float4*)(ro + e4 * 4) = make_float4(r[e4*4], r[e4*4+1], r[e4*4+2], r[e4*4+3]);

    out[I_OFF + (size_t)tokg * 2 + 0] = (float)i1;
    out[I_OFF + (size_t)tokg * 2 + 1] = (float)i2;

    float* go = out + G_OFF + (size_t)tokg * 16;
#pragma unroll
    for (int e4 = 0; e4 < 4; ++e4)
      *(float4*)(go + e4 * 4) = make_float4(g1[e4*4], g1[e4*4+1], g1[e4*4+2], g1[e4*4+3]);
  }
}

extern "C" void kernel_launch(void* const* d_in, const int* in_sizes, int n_in,
                              void* d_out, int out_size, void* d_ws, size_t ws_size,
                              hipStream_t stream) {
  const float* mh = (const float*)d_in[0];   // [8,4096,1024]
  const float* dt = (const float*)d_in[1];   // [8,4096,256]
  const float* dd = (const float*)d_in[2];   // [8,4096,256]
  const float* rg = (const float*)d_in[3];   // [8,4096,128]
  const float* de = (const float*)d_in[4];   // [8,4096,128]
  const float* ce = (const float*)d_in[5];   // [4,32]
  const float* wr = (const float*)d_in[6];   // [1824,16]
  const float* br = (const float*)d_in[7];   // [16]
  const float* wn = (const float*)d_in[8];   // [1824,16]
  const float* bn = (const float*)d_in[9];   // [16]
  const float* ep = (const float*)d_in[10];  // [8,4096,16]
  const int*   ci = (const int*)d_in[11];    // scalar
  float* out = (float*)d_out;

  router_kernel<<<512, 512, 0, stream>>>(mh, dt, dd, rg, de, ce, wr, br, wn, bn,
                                         ep, ci, out);
}